// Round 5
// baseline (245.777 us; speedup 1.0000x reference)
//
#include <hip/hip_runtime.h>
#include <math.h>

#define NQ 12
#define DIM 4096            // 2^12 amplitudes
#define NSAMP 2048          // 64*32 samples
#define NLAYERS 4

// Device-side constants: per-layer X3 (perm+transpose) address masks.
// phys(a_new) = XOR over set bits b of a_new of p[l][b]   (includes swizzle)
// write swizzle: gval(t) = XOR over set bits b of t of g[l][b] (4-bit values)
struct QConsts {
    unsigned short p[NLAYERS][12];
    unsigned short g[NLAYERS][8];
};

// GF(2) rank of low-4-bit values
static int gf2_rank4(const unsigned* vals, int n) {
    unsigned basis[4] = {0, 0, 0, 0};
    int r = 0;
    for (int i = 0; i < n; ++i) {
        unsigned v = vals[i] & 15u;
        while (v) {
            int b = 31 - __builtin_clz(v);
            if (basis[b]) v ^= basis[b];
            else { basis[b] = v; ++r; break; }
        }
    }
    return r;
}

static QConsts host_consts() {
    // CNOT-ring masks (verified in rounds 1-3): src(b) = XOR over set bits j of m[l][j]
    unsigned m[NLAYERS][12];
    for (int l = 0; l < NLAYERS; ++l) {
        int r = l % (NQ - 1) + 1;
        for (int j = 0; j < NQ; ++j) {
            unsigned v = 1u << j;
            for (int k = NQ - 1; k >= 0; --k) {
                int c = k, t = (k + r) % NQ;
                int pc = NQ - 1 - c, pt = NQ - 1 - t;
                if ((v >> pc) & 1u) v ^= (1u << pt);
            }
            m[l][j] = v;
        }
    }
    QConsts C{};
    unsigned seed = 0x12345u;
    auto rnd = [&]() { seed = seed * 1664525u + 1013904223u; return (seed >> 16) & 15u; };
    for (int l = 0; l < NLAYERS; ++l) {
        unsigned bestg[8] = {0,0,0,0,0,0,0,0};
        bool ok = false;
        for (int trial = 0; trial < 20000 && !ok; ++trial) {
            unsigned g[8];
            for (int b = 0; b < 8; ++b) g[b] = rnd();
            if (gf2_rank4(g, 6) != 4) continue;          // write-side balance
            unsigned p[12];
            for (int b = 0; b < 12; ++b) {
                unsigned mb = m[l][b];
                unsigned gv = 0, hb = (mb >> 4) & 255u;
                for (int c = 0; c < 8; ++c) if ((hb >> c) & 1u) gv ^= g[c];
                p[b] = mb ^ gv;
            }
            if (gf2_rank4(p, 6) != 4) continue;          // read-side balance
            ok = true;
            for (int b = 0; b < 8; ++b) bestg[b] = g[b];
        }
        // fill (fallback g=0 stays correct, just conflicted)
        for (int b = 0; b < 8; ++b) C.g[l][b] = (unsigned short)bestg[b];
        for (int b = 0; b < 12; ++b) {
            unsigned mb = m[l][b];
            unsigned gv = 0, hb = (mb >> 4) & 255u;
            for (int c = 0; c < 8; ++c) if ((hb >> c) & 1u) gv ^= bestg[c];
            C.p[l][b] = (unsigned short)(mb ^ gv);
        }
    }
    return C;
}

// ---------------- Kernel A: h = x_perm @ W_in^T + b_in + 1e-6 ----------------
// 128(k) x 128(s) tile per block, 8x8 micro-tile per thread, K=128 in 4 chunks.
__global__ __launch_bounds__(256) void gemm_in_kernel(
        const float* __restrict__ x, const float* __restrict__ Win,
        const float* __restrict__ bin, float* __restrict__ h) {
    __shared__ float xs[32 * 128];   // [l][s]
    __shared__ float ws[32 * 145];   // [l][k packed: k + (k>>3)], stride 145 (odd)
    const int tid = threadIdx.x;
    const int kBase = blockIdx.x * 128;
    const int sBase = blockIdx.y * 128;
    const int tk = tid & 15, ts = tid >> 4;
    float acc[8][8];
#pragma unroll
    for (int i = 0; i < 8; ++i)
#pragma unroll
        for (int j = 0; j < 8; ++j) acc[i][j] = 0.f;

#pragma unroll 1
    for (int kc = 0; kc < 4; ++kc) {
        __syncthreads();   // WAR vs previous chunk's reads
#pragma unroll
        for (int it = 0; it < 16; ++it) {
            int idx = it * 256 + tid;
            int sl = idx & 127, ll = idx >> 7;
            int s = sBase + sl;
            xs[ll * 128 + sl] =
                x[(s >> 5) * 4096 + (kc * 32 + ll) * 32 + (s & 31)];
        }
#pragma unroll
        for (int it = 0; it < 16; ++it) {
            int idx = it * 256 + tid;
            int ll = idx & 31, kk = idx >> 5;
            ws[ll * 145 + kk + (kk >> 3)] = Win[(kBase + kk) * 128 + kc * 32 + ll];
        }
        __syncthreads();
#pragma unroll
        for (int l = 0; l < 32; ++l) {
            float xv[8], wv[8];
            *(float4*)&xv[0] = *(const float4*)&xs[l * 128 + ts * 8];
            *(float4*)&xv[4] = *(const float4*)&xs[l * 128 + ts * 8 + 4];
#pragma unroll
            for (int c = 0; c < 8; ++c) wv[c] = ws[l * 145 + tk * 9 + c];
#pragma unroll
            for (int i = 0; i < 8; ++i)
#pragma unroll
                for (int j = 0; j < 8; ++j)
                    acc[i][j] = fmaf(wv[i], xv[j], acc[i][j]);
        }
    }
#pragma unroll
    for (int j = 0; j < 8; ++j) {
        int s = sBase + ts * 8 + j;
        float o[8];
#pragma unroll
        for (int i = 0; i < 8; ++i)
            o[i] = acc[i][j] + bin[kBase + tk * 8 + i] + 1e-6f;
        *(float4*)&h[(size_t)s * 4096 + kBase + tk * 8]     = *(float4*)&o[0];
        *(float4*)&h[(size_t)s * 4096 + kBase + tk * 8 + 4] = *(float4*)&o[4];
    }
}

// Rot gate on register bit Q using coeffs from LDS row U (wave-uniform).
#define ROT_PAIRS(GI, Q)                                                  \
    {                                                                     \
        const float* U = Ug[GI];                                          \
        const float u00r = U[0], u00i = U[1], u01r = U[2], u01i = U[3];   \
        const float u10r = U[4], u10i = U[5], u11r = U[6], u11i = U[7];   \
        _Pragma("unroll")                                                 \
        for (int j = 0; j < 16; ++j)                                      \
            if (!((j >> (Q)) & 1)) {                                      \
                const int j1 = j | (1 << (Q));                            \
                float2 a0 = v[j], a1 = v[j1];                             \
                v[j].x  = u00r*a0.x - u00i*a0.y + u01r*a1.x - u01i*a1.y;  \
                v[j].y  = u00r*a0.y + u00i*a0.x + u01r*a1.y + u01i*a1.x;  \
                v[j1].x = u10r*a0.x - u10i*a0.y + u11r*a1.x - u11i*a1.y;  \
                v[j1].y = u10r*a0.y + u10i*a0.x + u11r*a1.y + u11i*a1.x;  \
            }                                                             \
    }

// ---------------- Kernel B: register-resident qsim with corner-turns ---------
// Amp a = (j<<8)|t canonical.  Per layer: 4 reg gates (bits 11-8), X1 -> bits
// 7-4 local, 4 reg gates, X2 -> bits 3-0 local, 4 reg gates, X3 = CNOT perm +
// return to canonical.  All LDS passes XOR-swizzled for bank balance.
__global__ __launch_bounds__(256, 4) void qsim_kernel(
        const float* __restrict__ h, const float* __restrict__ qw,
        const float* __restrict__ Wout, const float* __restrict__ bout,
        float* __restrict__ out, QConsts C) {
    __shared__ float2 st[DIM];              // 32 KB
    __shared__ float Ug[NLAYERS * NQ][8];   // gate matrices
    __shared__ float red[4];
    __shared__ float wred[4][NQ];
    __shared__ float zsh[NQ];

    const int tid = threadIdx.x;
    const int samp = blockIdx.x;
    const int lane = tid & 63, wv = tid >> 6;

    // ---- Rot matrices (PennyLane Rot = RZ(om)RY(th)RZ(phi))
    if (tid < NLAYERS * NQ) {
        float phi = qw[tid * 3 + 0];
        float th  = qw[tid * 3 + 1];
        float om  = qw[tid * 3 + 2];
        float s, c, sa, ca, sb, cb;
        sincosf(0.5f * th, &s, &c);
        sincosf(0.5f * (phi + om), &sa, &ca);
        sincosf(0.5f * (phi - om), &sb, &cb);
        Ug[tid][0] =  c * ca;  Ug[tid][1] = -c * sa;   // u00
        Ug[tid][2] = -s * cb;  Ug[tid][3] = -s * sb;   // u01
        Ug[tid][4] =  s * cb;  Ug[tid][5] = -s * sb;   // u10
        Ug[tid][6] =  c * ca;  Ug[tid][7] =  c * sa;   // u11
    }

    // ---- load h row (coalesced), norm
    float vloc[16];
    float ss = 0.f;
#pragma unroll
    for (int j = 0; j < 16; ++j) {
        float t = h[(size_t)samp * DIM + (j << 8) + tid];
        vloc[j] = t;
        ss += t * t;
    }
#pragma unroll
    for (int o = 32; o > 0; o >>= 1) ss += __shfl_xor(ss, o);
    if (lane == 0) red[wv] = ss;
    __syncthreads();     // also covers Ug init
    const float inv = 1.0f / sqrtf(red[0] + red[1] + red[2] + red[3]);
    float2 v[16];
#pragma unroll
    for (int j = 0; j < 16; ++j) v[j] = make_float2(vloc[j] * inv, 0.f);

    const int tHi = tid >> 4, tLo = tid & 15;

#pragma unroll
    for (int l = 0; l < NLAYERS; ++l) {
        const int gb = l * NQ;

        // ---- stage A: wires 0-3 on reg bit q (amp bit 8+q, wire 3-q)
        ROT_PAIRS(gb + 3, 0)
        ROT_PAIRS(gb + 2, 1)
        ROT_PAIRS(gb + 1, 2)
        ROT_PAIRS(gb + 0, 3)

        // ---- X1: A -> B.  phi1(a) = a ^ ((a>>8)&15)
#pragma unroll
        for (int j = 0; j < 16; ++j) st[(j << 8) | (tid ^ j)] = v[j];
        __syncthreads();
        {
            const int rb = (tHi << 8) | (tLo ^ tHi);
#pragma unroll
            for (int j = 0; j < 16; ++j) v[j] = st[rb | (j << 4)];
        }
        __syncthreads();

        // ---- stage B: wires 4-7 on reg bit q (amp bit 4+q, wire 7-q)
        ROT_PAIRS(gb + 7, 0)
        ROT_PAIRS(gb + 6, 1)
        ROT_PAIRS(gb + 5, 2)
        ROT_PAIRS(gb + 4, 3)

        // ---- X2: B -> C.  phi2(a) = a ^ ((a>>4)&15)
        {
            const int hi8 = tHi << 8;
#pragma unroll
            for (int j = 0; j < 16; ++j)
                st[hi8 | (j << 4) | (tLo ^ j)] = v[j];
        }
        __syncthreads();
        {
            const int rb = tid << 4;
#pragma unroll
            for (int j = 0; j < 16; ++j) v[j] = st[rb | (tLo ^ j)];
        }
        __syncthreads();

        // ---- stage C: wires 8-11 on reg bit q (amp bit q, wire 11-q)
        ROT_PAIRS(gb + 11, 0)
        ROT_PAIRS(gb + 10, 1)
        ROT_PAIRS(gb + 9, 2)
        ROT_PAIRS(gb + 8, 3)

        // ---- X3: CNOT perm + back to canonical (host-searched swizzle)
        {
            unsigned gval = 0, pbase = 0;
#pragma unroll
            for (int b = 0; b < 8; ++b)
                if ((tid >> b) & 1) { gval ^= C.g[l][b]; pbase ^= C.p[l][b]; }
            const int wb = tid << 4;
#pragma unroll
            for (int j = 0; j < 16; ++j) st[wb | (j ^ (int)gval)] = v[j];
            __syncthreads();
            const unsigned c8 = C.p[l][8], c9 = C.p[l][9];
            const unsigned c10 = C.p[l][10], c11 = C.p[l][11];
#pragma unroll
            for (int j = 0; j < 16; ++j) {
                unsigned s = pbase;
                if (j & 1) s ^= c8;
                if (j & 2) s ^= c9;
                if (j & 4) s ^= c10;
                if (j & 8) s ^= c11;
                v[j] = st[s];
            }
            __syncthreads();
        }
    }

    // ---- PauliZ expvals: sign_i = bit (11-i) of a;  a = (j<<8)|tid
    float fs[12];
#pragma unroll
    for (int i = 0; i < 12; ++i)
        fs[i] = (i < 4) ? 1.f : (((tid >> (11 - i)) & 1) ? -1.f : 1.f);
    float zp[12];
#pragma unroll
    for (int i = 0; i < 12; ++i) zp[i] = 0.f;
#pragma unroll
    for (int j = 0; j < 16; ++j) {
        float2 a = v[j];
        float pr = a.x * a.x + a.y * a.y;
#pragma unroll
        for (int i = 0; i < 12; ++i) {
            const bool neg = (i < 4) && ((j >> (3 - i)) & 1);
            zp[i] = fmaf(pr, neg ? -fs[i] : fs[i], zp[i]);
        }
    }
#pragma unroll
    for (int i = 0; i < 12; ++i) {
        float z = zp[i];
#pragma unroll
        for (int o = 32; o > 0; o >>= 1) z += __shfl_xor(z, o);
        if (lane == 0) wred[wv][i] = z;
    }
    __syncthreads();
    if (tid < NQ)
        zsh[tid] = wred[0][tid] + wred[1][tid] + wred[2][tid] + wred[3][tid];
    __syncthreads();

    if (tid < 96) {
        float acc = bout[tid];
#pragma unroll
        for (int i = 0; i < NQ; ++i) acc += zsh[i] * Wout[tid * NQ + i];
        int b = samp >> 5, m = samp & 31;
        out[b * (96 * 32) + tid * 32 + m] = acc;
    }
}

extern "C" void kernel_launch(void* const* d_in, const int* in_sizes, int n_in,
                              void* d_out, int out_size, void* d_ws, size_t ws_size,
                              hipStream_t stream) {
    const float* x    = (const float*)d_in[0];
    const float* Win  = (const float*)d_in[1];
    const float* bin  = (const float*)d_in[2];
    const float* qw   = (const float*)d_in[3];
    const float* Wout = (const float*)d_in[4];
    const float* bout = (const float*)d_in[5];
    float* h = (float*)d_ws;   // 32 MB scratch

    QConsts C = host_consts();

    gemm_in_kernel<<<dim3(32, 16), 256, 0, stream>>>(x, Win, bin, h);
    qsim_kernel<<<dim3(NSAMP), 256, 0, stream>>>(h, qw, Wout, bout,
                                                 (float*)d_out, C);
}

// Round 6
// 199.228 us; speedup vs baseline: 1.2336x; 1.2336x over previous
//
#include <hip/hip_runtime.h>
#include <math.h>

#define NQ 12
#define DIM 4096            // 2^12 amplitudes
#define NSAMP 2048          // 64*32 samples
#define NLAYERS 4

// Device-side constants: per-layer X3 (perm+transpose) address masks.
// phys(a_new) = XOR over set bits b of a_new of p[l][b]   (includes swizzle)
// write swizzle: gval(t) = XOR over set bits b of t of g[l][b] (4-bit values)
struct QConsts {
    unsigned short p[NLAYERS][12];
    unsigned short g[NLAYERS][8];
};

// GF(2) rank of low-4-bit values
static int gf2_rank4(const unsigned* vals, int n) {
    unsigned basis[4] = {0, 0, 0, 0};
    int r = 0;
    for (int i = 0; i < n; ++i) {
        unsigned v = vals[i] & 15u;
        while (v) {
            int b = 31 - __builtin_clz(v);
            if (basis[b]) v ^= basis[b];
            else { basis[b] = v; ++r; break; }
        }
    }
    return r;
}

static QConsts host_consts() {
    // CNOT-ring masks (verified rounds 1-5): src(b) = XOR over set bits j of m[l][j]
    unsigned m[NLAYERS][12];
    for (int l = 0; l < NLAYERS; ++l) {
        int r = l % (NQ - 1) + 1;
        for (int j = 0; j < NQ; ++j) {
            unsigned v = 1u << j;
            for (int k = NQ - 1; k >= 0; --k) {
                int c = k, t = (k + r) % NQ;
                int pc = NQ - 1 - c, pt = NQ - 1 - t;
                if ((v >> pc) & 1u) v ^= (1u << pt);
            }
            m[l][j] = v;
        }
    }
    QConsts C{};
    unsigned seed = 0x12345u;
    auto rnd = [&]() { seed = seed * 1664525u + 1013904223u; return (seed >> 16) & 15u; };
    for (int l = 0; l < NLAYERS; ++l) {
        unsigned bestg[8] = {0,0,0,0,0,0,0,0};
        bool ok = false;
        for (int trial = 0; trial < 20000 && !ok; ++trial) {
            unsigned g[8];
            for (int b = 0; b < 8; ++b) g[b] = rnd();
            if (gf2_rank4(g, 6) != 4) continue;          // write-side balance
            unsigned p[12];
            for (int b = 0; b < 12; ++b) {
                unsigned mb = m[l][b];
                unsigned gv = 0, hb = (mb >> 4) & 255u;
                for (int c = 0; c < 8; ++c) if ((hb >> c) & 1u) gv ^= g[c];
                p[b] = mb ^ gv;
            }
            if (gf2_rank4(p, 6) != 4) continue;          // read-side balance
            ok = true;
            for (int b = 0; b < 8; ++b) bestg[b] = g[b];
        }
        for (int b = 0; b < 8; ++b) C.g[l][b] = (unsigned short)bestg[b];
        for (int b = 0; b < 12; ++b) {
            unsigned mb = m[l][b];
            unsigned gv = 0, hb = (mb >> 4) & 255u;
            for (int c = 0; c < 8; ++c) if ((hb >> c) & 1u) gv ^= bestg[c];
            C.p[l][b] = (unsigned short)(mb ^ gv);
        }
    }
    return C;
}

// ---------------- Kernel A: h = x_perm @ W_in^T + b_in + 1e-6 ----------------
// 128(k) x 128(s) tile per block, 8x8 micro-tile per thread, K=128 in 4 chunks.
__global__ __launch_bounds__(256) void gemm_in_kernel(
        const float* __restrict__ x, const float* __restrict__ Win,
        const float* __restrict__ bin, float* __restrict__ h) {
    __shared__ float xs[32 * 128];   // [l][s]
    __shared__ float ws[32 * 145];   // [l][k packed: k + (k>>3)], stride 145 (odd)
    const int tid = threadIdx.x;
    const int kBase = blockIdx.x * 128;
    const int sBase = blockIdx.y * 128;
    const int tk = tid & 15, ts = tid >> 4;
    float acc[8][8];
#pragma unroll
    for (int i = 0; i < 8; ++i)
#pragma unroll
        for (int j = 0; j < 8; ++j) acc[i][j] = 0.f;

#pragma unroll 1
    for (int kc = 0; kc < 4; ++kc) {
        __syncthreads();   // WAR vs previous chunk's reads
#pragma unroll
        for (int it = 0; it < 16; ++it) {
            int idx = it * 256 + tid;
            int sl = idx & 127, ll = idx >> 7;
            int s = sBase + sl;
            xs[ll * 128 + sl] =
                x[(s >> 5) * 4096 + (kc * 32 + ll) * 32 + (s & 31)];
        }
#pragma unroll
        for (int it = 0; it < 16; ++it) {
            int idx = it * 256 + tid;
            int ll = idx & 31, kk = idx >> 5;
            ws[ll * 145 + kk + (kk >> 3)] = Win[(kBase + kk) * 128 + kc * 32 + ll];
        }
        __syncthreads();
#pragma unroll
        for (int l = 0; l < 32; ++l) {
            float xv[8], wv[8];
            *(float4*)&xv[0] = *(const float4*)&xs[l * 128 + ts * 8];
            *(float4*)&xv[4] = *(const float4*)&xs[l * 128 + ts * 8 + 4];
#pragma unroll
            for (int c = 0; c < 8; ++c) wv[c] = ws[l * 145 + tk * 9 + c];
#pragma unroll
            for (int i = 0; i < 8; ++i)
#pragma unroll
                for (int j = 0; j < 8; ++j)
                    acc[i][j] = fmaf(wv[i], xv[j], acc[i][j]);
        }
    }
#pragma unroll
    for (int j = 0; j < 8; ++j) {
        int s = sBase + ts * 8 + j;
        float o[8];
#pragma unroll
        for (int i = 0; i < 8; ++i)
            o[i] = acc[i][j] + bin[kBase + tk * 8 + i] + 1e-6f;
        *(float4*)&h[(size_t)s * 4096 + kBase + tk * 8]     = *(float4*)&o[0];
        *(float4*)&h[(size_t)s * 4096 + kBase + tk * 8 + 4] = *(float4*)&o[4];
    }
}

// Rot gate on register bit Q using coeffs from LDS row U (wave-uniform).
#define ROT_PAIRS(GI, Q)                                                  \
    {                                                                     \
        const float* U = Ug[GI];                                          \
        const float u00r = U[0], u00i = U[1], u01r = U[2], u01i = U[3];   \
        const float u10r = U[4], u10i = U[5], u11r = U[6], u11i = U[7];   \
        _Pragma("unroll")                                                 \
        for (int j = 0; j < 16; ++j)                                      \
            if (!((j >> (Q)) & 1)) {                                      \
                const int j1 = j | (1 << (Q));                            \
                float2 a0 = v[j], a1 = v[j1];                             \
                v[j].x  = u00r*a0.x - u00i*a0.y + u01r*a1.x - u01i*a1.y;  \
                v[j].y  = u00r*a0.y + u00i*a0.x + u01r*a1.y + u01i*a1.x;  \
                v[j1].x = u10r*a0.x - u10i*a0.y + u11r*a1.x - u11i*a1.y;  \
                v[j1].y = u10r*a0.y + u10i*a0.x + u11r*a1.y + u11i*a1.x;  \
            }                                                             \
    }

// ---------------- Kernel B: register-resident qsim with corner-turns ---------
// Amp a = (j<<8)|t canonical.  Per layer: 4 reg gates (bits 11-8), X1 -> bits
// 7-4 local, 4 reg gates, X2 -> bits 3-0 local, 4 reg gates, X3 = CNOT perm +
// return to canonical.  All LDS passes XOR-swizzled for bank balance.
// launch_bounds(256,2): allow up to 256 VGPR — spilling to scratch cost 2.5x
// in round 5 (199 MB scratch writes); LDS (34 KB) caps blocks/CU at 4 anyway.
__global__ __launch_bounds__(256, 2) void qsim_kernel(
        const float* __restrict__ h, const float* __restrict__ qw,
        const float* __restrict__ Wout, const float* __restrict__ bout,
        float* __restrict__ out, QConsts C) {
    __shared__ float2 st[DIM];              // 32 KB
    __shared__ float Ug[NLAYERS * NQ][8];   // gate matrices
    __shared__ float red[4];
    __shared__ float wred[4][NQ];
    __shared__ float zsh[NQ];

    const int tid = threadIdx.x;
    const int samp = blockIdx.x;
    const int lane = tid & 63, wv = tid >> 6;

    // ---- Rot matrices (PennyLane Rot = RZ(om)RY(th)RZ(phi))
    if (tid < NLAYERS * NQ) {
        float phi = qw[tid * 3 + 0];
        float th  = qw[tid * 3 + 1];
        float om  = qw[tid * 3 + 2];
        float s, c, sa, ca, sb, cb;
        sincosf(0.5f * th, &s, &c);
        sincosf(0.5f * (phi + om), &sa, &ca);
        sincosf(0.5f * (phi - om), &sb, &cb);
        Ug[tid][0] =  c * ca;  Ug[tid][1] = -c * sa;   // u00
        Ug[tid][2] = -s * cb;  Ug[tid][3] = -s * sb;   // u01
        Ug[tid][4] =  s * cb;  Ug[tid][5] = -s * sb;   // u10
        Ug[tid][6] =  c * ca;  Ug[tid][7] =  c * sa;   // u11
    }

    // ---- load h row directly into state (coalesced), compute norm
    float2 v[16];
    float ss = 0.f;
#pragma unroll
    for (int j = 0; j < 16; ++j) {
        float t = h[(size_t)samp * DIM + (j << 8) + tid];
        v[j].x = t;
        v[j].y = 0.f;
        ss += t * t;
    }
#pragma unroll
    for (int o = 32; o > 0; o >>= 1) ss += __shfl_xor(ss, o);
    if (lane == 0) red[wv] = ss;
    __syncthreads();     // also covers Ug init
    const float inv = 1.0f / sqrtf(red[0] + red[1] + red[2] + red[3]);
#pragma unroll
    for (int j = 0; j < 16; ++j) v[j].x *= inv;

    const int tHi = tid >> 4, tLo = tid & 15;

#pragma unroll 1
    for (int l = 0; l < NLAYERS; ++l) {
        const int gb = l * NQ;

        // ---- stage A: wires 0-3 on reg bit q (amp bit 8+q, wire 3-q)
        ROT_PAIRS(gb + 3, 0)
        ROT_PAIRS(gb + 2, 1)
        ROT_PAIRS(gb + 1, 2)
        ROT_PAIRS(gb + 0, 3)

        // ---- X1: A -> B.  phi1(a) = a ^ ((a>>8)&15)
#pragma unroll
        for (int j = 0; j < 16; ++j) st[(j << 8) | (tid ^ j)] = v[j];
        __syncthreads();
        {
            const int rb = (tHi << 8) | (tLo ^ tHi);
#pragma unroll
            for (int j = 0; j < 16; ++j) v[j] = st[rb | (j << 4)];
        }
        __syncthreads();

        // ---- stage B: wires 4-7 on reg bit q (amp bit 4+q, wire 7-q)
        ROT_PAIRS(gb + 7, 0)
        ROT_PAIRS(gb + 6, 1)
        ROT_PAIRS(gb + 5, 2)
        ROT_PAIRS(gb + 4, 3)

        // ---- X2: B -> C.  phi2(a) = a ^ ((a>>4)&15)
        {
            const int hi8 = tHi << 8;
#pragma unroll
            for (int j = 0; j < 16; ++j)
                st[hi8 | (j << 4) | (tLo ^ j)] = v[j];
        }
        __syncthreads();
        {
            const int rb = tid << 4;
#pragma unroll
            for (int j = 0; j < 16; ++j) v[j] = st[rb | (tLo ^ j)];
        }
        __syncthreads();

        // ---- stage C: wires 8-11 on reg bit q (amp bit q, wire 11-q)
        ROT_PAIRS(gb + 11, 0)
        ROT_PAIRS(gb + 10, 1)
        ROT_PAIRS(gb + 9, 2)
        ROT_PAIRS(gb + 8, 3)

        // ---- X3: CNOT perm + back to canonical (host-searched swizzle)
        {
            unsigned gval = 0, pbase = 0;
#pragma unroll
            for (int b = 0; b < 8; ++b)
                if ((tid >> b) & 1) { gval ^= C.g[l][b]; pbase ^= C.p[l][b]; }
            const int wb = tid << 4;
#pragma unroll
            for (int j = 0; j < 16; ++j) st[wb | (j ^ (int)gval)] = v[j];
            __syncthreads();
            const unsigned c8 = C.p[l][8], c9 = C.p[l][9];
            const unsigned c10 = C.p[l][10], c11 = C.p[l][11];
#pragma unroll
            for (int j = 0; j < 16; ++j) {
                unsigned s = pbase;
                if (j & 1) s ^= c8;
                if (j & 2) s ^= c9;
                if (j & 4) s ^= c10;
                if (j & 8) s ^= c11;
                v[j] = st[s];
            }
            __syncthreads();
        }
    }

    // ---- PauliZ expvals: sign_i = bit (11-i) of a;  a = (j<<8)|tid
    float fs[12];
#pragma unroll
    for (int i = 0; i < 12; ++i)
        fs[i] = (i < 4) ? 1.f : (((tid >> (11 - i)) & 1) ? -1.f : 1.f);
    float zp[12];
#pragma unroll
    for (int i = 0; i < 12; ++i) zp[i] = 0.f;
#pragma unroll
    for (int j = 0; j < 16; ++j) {
        float2 a = v[j];
        float pr = a.x * a.x + a.y * a.y;
#pragma unroll
        for (int i = 0; i < 12; ++i) {
            const bool neg = (i < 4) && ((j >> (3 - i)) & 1);
            zp[i] = fmaf(pr, neg ? -fs[i] : fs[i], zp[i]);
        }
    }
#pragma unroll
    for (int i = 0; i < 12; ++i) {
        float z = zp[i];
#pragma unroll
        for (int o = 32; o > 0; o >>= 1) z += __shfl_xor(z, o);
        if (lane == 0) wred[wv][i] = z;
    }
    __syncthreads();
    if (tid < NQ)
        zsh[tid] = wred[0][tid] + wred[1][tid] + wred[2][tid] + wred[3][tid];
    __syncthreads();

    if (tid < 96) {
        float acc = bout[tid];
#pragma unroll
        for (int i = 0; i < NQ; ++i) acc += zsh[i] * Wout[tid * NQ + i];
        int b = samp >> 5, m = samp & 31;
        out[b * (96 * 32) + tid * 32 + m] = acc;
    }
}

extern "C" void kernel_launch(void* const* d_in, const int* in_sizes, int n_in,
                              void* d_out, int out_size, void* d_ws, size_t ws_size,
                              hipStream_t stream) {
    const float* x    = (const float*)d_in[0];
    const float* Win  = (const float*)d_in[1];
    const float* bin  = (const float*)d_in[2];
    const float* qw   = (const float*)d_in[3];
    const float* Wout = (const float*)d_in[4];
    const float* bout = (const float*)d_in[5];
    float* h = (float*)d_ws;   // 32 MB scratch

    QConsts C = host_consts();

    gemm_in_kernel<<<dim3(32, 16), 256, 0, stream>>>(x, Win, bin, h);
    qsim_kernel<<<dim3(NSAMP), 256, 0, stream>>>(h, qw, Wout, bout,
                                                 (float*)d_out, C);
}

// Round 8
// 136.490 us; speedup vs baseline: 1.8007x; 1.4597x over previous
//
#include <hip/hip_runtime.h>
#include <math.h>

#define NQ 12
#define DIM 4096            // 2^12 amplitudes
#define NSAMP 2048          // 64*32 samples
#define NLAYERS 4

typedef float v2f __attribute__((ext_vector_type(2)));
#define SWV(a) __builtin_shufflevector((a), (a), 1, 0)

// Device-side constants: per-layer X3 (perm+transpose) address masks.
// phys(a_new) = XOR over set bits b of a_new of p[l][b]   (includes swizzle)
// write swizzle: gval(t) = XOR over set bits b of t of g[l][b] (4-bit values)
struct QConsts {
    unsigned short p[NLAYERS][12];
    unsigned short g[NLAYERS][8];
};

// GF(2) rank of low-4-bit values
static int gf2_rank4(const unsigned* vals, int n) {
    unsigned basis[4] = {0, 0, 0, 0};
    int r = 0;
    for (int i = 0; i < n; ++i) {
        unsigned v = vals[i] & 15u;
        while (v) {
            int b = 31 - __builtin_clz(v);
            if (basis[b]) v ^= basis[b];
            else { basis[b] = v; ++r; break; }
        }
    }
    return r;
}

static QConsts host_consts() {
    // CNOT-ring masks (verified rounds 1-6): src(b) = XOR over set bits j of m[l][j]
    unsigned m[NLAYERS][12];
    for (int l = 0; l < NLAYERS; ++l) {
        int r = l % (NQ - 1) + 1;
        for (int j = 0; j < NQ; ++j) {
            unsigned v = 1u << j;
            for (int k = NQ - 1; k >= 0; --k) {
                int c = k, t = (k + r) % NQ;
                int pc = NQ - 1 - c, pt = NQ - 1 - t;
                if ((v >> pc) & 1u) v ^= (1u << pt);
            }
            m[l][j] = v;
        }
    }
    QConsts C{};
    unsigned seed = 0x12345u;
    auto rnd = [&]() { seed = seed * 1664525u + 1013904223u; return (seed >> 16) & 15u; };
    for (int l = 0; l < NLAYERS; ++l) {
        unsigned bestg[8] = {0,0,0,0,0,0,0,0};
        bool ok = false;
        for (int trial = 0; trial < 20000 && !ok; ++trial) {
            unsigned g[8];
            for (int b = 0; b < 8; ++b) g[b] = rnd();
            if (gf2_rank4(g, 6) != 4) continue;          // write-side balance
            unsigned p[12];
            for (int b = 0; b < 12; ++b) {
                unsigned mb = m[l][b];
                unsigned gv = 0, hb = (mb >> 4) & 255u;
                for (int c = 0; c < 8; ++c) if ((hb >> c) & 1u) gv ^= g[c];
                p[b] = mb ^ gv;
            }
            if (gf2_rank4(p, 6) != 4) continue;          // read-side balance
            ok = true;
            for (int b = 0; b < 8; ++b) bestg[b] = g[b];
        }
        for (int b = 0; b < 8; ++b) C.g[l][b] = (unsigned short)bestg[b];
        for (int b = 0; b < 12; ++b) {
            unsigned mb = m[l][b];
            unsigned gv = 0, hb = (mb >> 4) & 255u;
            for (int c = 0; c < 8; ++c) if ((hb >> c) & 1u) gv ^= bestg[c];
            C.p[l][b] = (unsigned short)(mb ^ gv);
        }
    }
    return C;
}

// ---------------- Kernel A: h = x_perm @ W_in^T + b_in + 1e-6 ----------------
// 128(k) x 128(s) tile per block, 8x8 micro-tile per thread, K=128 in 4 chunks.
__global__ __launch_bounds__(256) void gemm_in_kernel(
        const float* __restrict__ x, const float* __restrict__ Win,
        const float* __restrict__ bin, float* __restrict__ h) {
    __shared__ float xs[32 * 128];   // [l][s]
    __shared__ float ws[32 * 145];   // [l][k packed: k + (k>>3)], stride 145 (odd)
    const int tid = threadIdx.x;
    const int kBase = blockIdx.x * 128;
    const int sBase = blockIdx.y * 128;
    const int tk = tid & 15, ts = tid >> 4;
    float acc[8][8];
#pragma unroll
    for (int i = 0; i < 8; ++i)
#pragma unroll
        for (int j = 0; j < 8; ++j) acc[i][j] = 0.f;

#pragma unroll 1
    for (int kc = 0; kc < 4; ++kc) {
        __syncthreads();   // WAR vs previous chunk's reads
#pragma unroll
        for (int it = 0; it < 16; ++it) {
            int idx = it * 256 + tid;
            int sl = idx & 127, ll = idx >> 7;
            int s = sBase + sl;
            xs[ll * 128 + sl] =
                x[(s >> 5) * 4096 + (kc * 32 + ll) * 32 + (s & 31)];
        }
#pragma unroll
        for (int it = 0; it < 16; ++it) {
            int idx = it * 256 + tid;
            int ll = idx & 31, kk = idx >> 5;
            ws[ll * 145 + kk + (kk >> 3)] = Win[(kBase + kk) * 128 + kc * 32 + ll];
        }
        __syncthreads();
#pragma unroll
        for (int l = 0; l < 32; ++l) {
            float xv[8], wv[8];
            *(float4*)&xv[0] = *(const float4*)&xs[l * 128 + ts * 8];
            *(float4*)&xv[4] = *(const float4*)&xs[l * 128 + ts * 8 + 4];
#pragma unroll
            for (int c = 0; c < 8; ++c) wv[c] = ws[l * 145 + tk * 9 + c];
#pragma unroll
            for (int i = 0; i < 8; ++i)
#pragma unroll
                for (int j = 0; j < 8; ++j)
                    acc[i][j] = fmaf(wv[i], xv[j], acc[i][j]);
        }
    }
#pragma unroll
    for (int j = 0; j < 8; ++j) {
        int s = sBase + ts * 8 + j;
        float o[8];
#pragma unroll
        for (int i = 0; i < 8; ++i)
            o[i] = acc[i][j] + bin[kBase + tk * 8 + i] + 1e-6f;
        *(float4*)&h[(size_t)s * 4096 + kBase + tk * 8]     = *(float4*)&o[0];
        *(float4*)&h[(size_t)s * 4096 + kBase + tk * 8 + 4] = *(float4*)&o[4];
    }
}

// Packed-complex Rot gate on register bit Q.  For complex z and unitary row
// (ur + i*ui):  (ur+i*ui)*z = ur*z + ui*J(z),  J(z) = (-z.im, z.re).
// v2f + shufflevector lets the backend emit v_pk_fma_f32 (+op_sel): 2 FLOP/inst.
#define ROT_PK(GI, Q)                                                     \
    {                                                                     \
        const float* U = Ug[GI];                                          \
        const float u00r = U[0], u01r = U[2], u10r = U[4], u11r = U[6];   \
        const v2f i00 = {-U[1], U[1]}, i01 = {-U[3], U[3]};               \
        const v2f i10 = {-U[5], U[5]}, i11 = {-U[7], U[7]};               \
        _Pragma("unroll")                                                 \
        for (int j = 0; j < 16; ++j)                                      \
            if (!((j >> (Q)) & 1)) {                                      \
                const int j1 = j | (1 << (Q));                            \
                v2f a0 = v[j], a1 = v[j1];                                \
                v2f s0 = SWV(a0), s1 = SWV(a1);                           \
                v[j]  = a0 * u00r + s0 * i00 + a1 * u01r + s1 * i01;      \
                v[j1] = a0 * u10r + s0 * i10 + a1 * u11r + s1 * i11;      \
            }                                                             \
    }

// ---------------- Kernel B: register-resident qsim with corner-turns ---------
// Amp a = (j<<8)|t canonical.  Per layer: 4 reg gates (bits 11-8), X1 -> bits
// 7-4 local, 4 reg gates, X2 -> bits 3-0 local, 4 reg gates, X3 = CNOT perm +
// return to canonical.  All LDS passes XOR-swizzled for bank balance.
// launch_bounds(256,2): spilling cost 2.5x in round 5 (199 MB scratch writes).
__global__ __launch_bounds__(256, 2) void qsim_kernel(
        const float* __restrict__ h, const float* __restrict__ qw,
        const float* __restrict__ Wout, const float* __restrict__ bout,
        float* __restrict__ out, QConsts C) {
    __shared__ v2f st[DIM];                 // 32 KB
    __shared__ float Ug[NLAYERS * NQ][8];   // gate matrices
    __shared__ float red[4];
    __shared__ float wred[4][NQ];
    __shared__ float zsh[NQ];

    const int tid = threadIdx.x;
    const int samp = blockIdx.x;
    const int lane = tid & 63, wv = tid >> 6;

    // ---- Rot matrices (PennyLane Rot = RZ(om)RY(th)RZ(phi))
    if (tid < NLAYERS * NQ) {
        float phi = qw[tid * 3 + 0];
        float th  = qw[tid * 3 + 1];
        float om  = qw[tid * 3 + 2];
        float s, c, sa, ca, sb, cb;
        sincosf(0.5f * th, &s, &c);
        sincosf(0.5f * (phi + om), &sa, &ca);
        sincosf(0.5f * (phi - om), &sb, &cb);
        Ug[tid][0] =  c * ca;  Ug[tid][1] = -c * sa;   // u00
        Ug[tid][2] = -s * cb;  Ug[tid][3] = -s * sb;   // u01
        Ug[tid][4] =  s * cb;  Ug[tid][5] = -s * sb;   // u10
        Ug[tid][6] =  c * ca;  Ug[tid][7] =  c * sa;   // u11
    }

    // ---- load h row directly into state (coalesced), compute norm
    v2f v[16];
    float ss = 0.f;
#pragma unroll
    for (int j = 0; j < 16; ++j) {
        float t = h[(size_t)samp * DIM + (j << 8) + tid];
        v[j][0] = t;
        v[j][1] = 0.f;
        ss += t * t;
    }
#pragma unroll
    for (int o = 32; o > 0; o >>= 1) ss += __shfl_xor(ss, o);
    if (lane == 0) red[wv] = ss;
    __syncthreads();     // also covers Ug init
    const float inv = 1.0f / sqrtf(red[0] + red[1] + red[2] + red[3]);
#pragma unroll
    for (int j = 0; j < 16; ++j) v[j][0] *= inv;

    const int tHi = tid >> 4, tLo = tid & 15;

#pragma unroll 1
    for (int l = 0; l < NLAYERS; ++l) {
        const int gb = l * NQ;

        // ---- stage A: wires 0-3 on reg bit q (amp bit 8+q, wire 3-q)
        ROT_PK(gb + 3, 0)
        ROT_PK(gb + 2, 1)
        ROT_PK(gb + 1, 2)
        ROT_PK(gb + 0, 3)

        // ---- X1: A -> B.  phi1(a) = a ^ ((a>>8)&15)
#pragma unroll
        for (int j = 0; j < 16; ++j) st[(j << 8) | (tid ^ j)] = v[j];
        __syncthreads();
        {
            const int rb = (tHi << 8) | (tLo ^ tHi);
#pragma unroll
            for (int j = 0; j < 16; ++j) v[j] = st[rb | (j << 4)];
        }
        __syncthreads();

        // ---- stage B: wires 4-7 on reg bit q (amp bit 4+q, wire 7-q)
        ROT_PK(gb + 7, 0)
        ROT_PK(gb + 6, 1)
        ROT_PK(gb + 5, 2)
        ROT_PK(gb + 4, 3)

        // ---- X2: B -> C.  phi2(a) = a ^ ((a>>4)&15)
        {
            const int hi8 = tHi << 8;
#pragma unroll
            for (int j = 0; j < 16; ++j)
                st[hi8 | (j << 4) | (tLo ^ j)] = v[j];
        }
        __syncthreads();
        {
            const int rb = tid << 4;
#pragma unroll
            for (int j = 0; j < 16; ++j) v[j] = st[rb | (tLo ^ j)];
        }
        __syncthreads();

        // ---- stage C: wires 8-11 on reg bit q (amp bit q, wire 11-q)
        ROT_PK(gb + 11, 0)
        ROT_PK(gb + 10, 1)
        ROT_PK(gb + 9, 2)
        ROT_PK(gb + 8, 3)

        // ---- X3: CNOT perm + back to canonical (host-searched swizzle)
        {
            unsigned gval = 0, pbase = 0;
#pragma unroll
            for (int b = 0; b < 8; ++b)
                if ((tid >> b) & 1) { gval ^= C.g[l][b]; pbase ^= C.p[l][b]; }
            const int wb = tid << 4;
#pragma unroll
            for (int j = 0; j < 16; ++j) st[wb | (j ^ (int)gval)] = v[j];
            __syncthreads();
            const unsigned c8 = C.p[l][8], c9 = C.p[l][9];
            const unsigned c10 = C.p[l][10], c11 = C.p[l][11];
#pragma unroll
            for (int j = 0; j < 16; ++j) {
                unsigned s = pbase;
                if (j & 1) s ^= c8;
                if (j & 2) s ^= c9;
                if (j & 4) s ^= c10;
                if (j & 8) s ^= c11;
                v[j] = st[s];
            }
            __syncthreads();
        }
    }

    // ---- PauliZ expvals.  a = (j<<8)|tid; sign_i = bit (11-i) of a.
    // For i<4 sign depends on j only; for i>=4 on tid only -> factor out P.
    float P = 0.f;
    float z03[4] = {0.f, 0.f, 0.f, 0.f};
#pragma unroll
    for (int j = 0; j < 16; ++j) {
        float pr = v[j][0] * v[j][0] + v[j][1] * v[j][1];
        P += pr;
#pragma unroll
        for (int i = 0; i < 4; ++i)
            z03[i] += ((j >> (3 - i)) & 1) ? -pr : pr;
    }
    float zv[12];
#pragma unroll
    for (int i = 0; i < 4; ++i) zv[i] = z03[i];
#pragma unroll
    for (int i = 4; i < 12; ++i)
        zv[i] = ((tid >> (11 - i)) & 1) ? -P : P;
#pragma unroll
    for (int i = 0; i < 12; ++i) {
        float z = zv[i];
#pragma unroll
        for (int o = 32; o > 0; o >>= 1) z += __shfl_xor(z, o);
        if (lane == 0) wred[wv][i] = z;
    }
    __syncthreads();
    if (tid < NQ)
        zsh[tid] = wred[0][tid] + wred[1][tid] + wred[2][tid] + wred[3][tid];
    __syncthreads();

    if (tid < 96) {
        float acc = bout[tid];
#pragma unroll
        for (int i = 0; i < NQ; ++i) acc += zsh[i] * Wout[tid * NQ + i];
        int b = samp >> 5, m = samp & 31;
        out[b * (96 * 32) + tid * 32 + m] = acc;
    }
}

extern "C" void kernel_launch(void* const* d_in, const int* in_sizes, int n_in,
                              void* d_out, int out_size, void* d_ws, size_t ws_size,
                              hipStream_t stream) {
    const float* x    = (const float*)d_in[0];
    const float* Win  = (const float*)d_in[1];
    const float* bin  = (const float*)d_in[2];
    const float* qw   = (const float*)d_in[3];
    const float* Wout = (const float*)d_in[4];
    const float* bout = (const float*)d_in[5];
    float* h = (float*)d_ws;   // 32 MB scratch

    QConsts C = host_consts();

    gemm_in_kernel<<<dim3(32, 16), 256, 0, stream>>>(x, Win, bin, h);
    qsim_kernel<<<dim3(NSAMP), 256, 0, stream>>>(h, qw, Wout, bout,
                                                 (float*)d_out, C);
}

// Round 9
// 107.420 us; speedup vs baseline: 2.2880x; 1.2706x over previous
//
#include <hip/hip_runtime.h>
#include <math.h>

#define NQ 12
#define DIM 4096            // 2^12 amplitudes
#define NSAMP 2048          // 64*32 samples
#define NLAYERS 4

typedef float v2f __attribute__((ext_vector_type(2)));
typedef short s8v __attribute__((ext_vector_type(8)));   // 8 bf16 raw bits
typedef float f4v __attribute__((ext_vector_type(4)));
#define SWV(a) __builtin_shufflevector((a), (a), 1, 0)

struct QConsts {
    unsigned short p[NLAYERS][12];
    unsigned short g[NLAYERS][8];
};

static int gf2_rank4(const unsigned* vals, int n) {
    unsigned basis[4] = {0, 0, 0, 0};
    int r = 0;
    for (int i = 0; i < n; ++i) {
        unsigned v = vals[i] & 15u;
        while (v) {
            int b = 31 - __builtin_clz(v);
            if (basis[b]) v ^= basis[b];
            else { basis[b] = v; ++r; break; }
        }
    }
    return r;
}

static QConsts host_consts() {
    // CNOT-ring masks (verified rounds 1-8): src(b) = XOR over set bits j of m[l][j]
    unsigned m[NLAYERS][12];
    for (int l = 0; l < NLAYERS; ++l) {
        int r = l % (NQ - 1) + 1;
        for (int j = 0; j < NQ; ++j) {
            unsigned v = 1u << j;
            for (int k = NQ - 1; k >= 0; --k) {
                int c = k, t = (k + r) % NQ;
                int pc = NQ - 1 - c, pt = NQ - 1 - t;
                if ((v >> pc) & 1u) v ^= (1u << pt);
            }
            m[l][j] = v;
        }
    }
    QConsts C{};
    unsigned seed = 0x12345u;
    auto rnd = [&]() { seed = seed * 1664525u + 1013904223u; return (seed >> 16) & 15u; };
    for (int l = 0; l < NLAYERS; ++l) {
        unsigned bestg[8] = {0,0,0,0,0,0,0,0};
        bool ok = false;
        for (int trial = 0; trial < 20000 && !ok; ++trial) {
            unsigned g[8];
            for (int b = 0; b < 8; ++b) g[b] = rnd();
            if (gf2_rank4(g, 6) != 4) continue;          // write-side balance
            unsigned p[12];
            for (int b = 0; b < 12; ++b) {
                unsigned mb = m[l][b];
                unsigned gv = 0, hb = (mb >> 4) & 255u;
                for (int c = 0; c < 8; ++c) if ((hb >> c) & 1u) gv ^= g[c];
                p[b] = mb ^ gv;
            }
            if (gf2_rank4(p, 6) != 4) continue;          // read-side balance
            ok = true;
            for (int b = 0; b < 8; ++b) bestg[b] = g[b];
        }
        for (int b = 0; b < 8; ++b) C.g[l][b] = (unsigned short)bestg[b];
        for (int b = 0; b < 12; ++b) {
            unsigned mb = m[l][b];
            unsigned gv = 0, hb = (mb >> 4) & 255u;
            for (int c = 0; c < 8; ++c) if ((hb >> c) & 1u) gv ^= bestg[c];
            C.p[l][b] = (unsigned short)(mb ^ gv);
        }
    }
    return C;
}

// ---------------- fp32 <-> bf16 split helpers -------------------------------
__device__ __forceinline__ unsigned short f2bf(float f) {
    unsigned u = __builtin_bit_cast(unsigned, f);
    return (unsigned short)((u + 0x7FFFu + ((u >> 16) & 1u)) >> 16);   // RNE
}
__device__ __forceinline__ float bf2f(unsigned short b) {
    unsigned u = ((unsigned)b) << 16;
    return __builtin_bit_cast(float, u);
}

// ---------------- Kernel A: MFMA bf16-split GEMM ----------------------------
// h[s,k] = sum_l x_p[s,l]*Win[k,l] + b_in[k] + 1e-6.
// D = A*B: A = Win tile (M=64 k x K), B = x_p^T tile (K x N=64 s).
// Split fp32 = hi(bf16) + lo(bf16); D ~= Ah*Bh + Ah*Bl + Al*Bh (fp32 acc).
// mfma_f32_16x16x32_bf16 layouts (m89-verified): A row=lane&15,k=8*(lane>>4)+e;
// B col=lane&15 same k; D col=lane&15, row=4*(lane>>4)+reg.
#define LDA 72   // 64 + 8 pad shorts: 144 B row stride -> conflict-light
__global__ __launch_bounds__(256) void gemm_in_mfma(
        const float* __restrict__ x, const float* __restrict__ Win,
        const float* __restrict__ bin, float* __restrict__ h) {
    __shared__ unsigned short Ah[64 * LDA], Al[64 * LDA];
    __shared__ unsigned short Bh[64 * LDA], Bl[64 * LDA];
    const int tid = threadIdx.x;
    const int kBase = blockIdx.x * 64;
    const int sBase = blockIdx.y * 64;
    const int lane = tid & 63, wid = tid >> 6;
    const int wr = wid >> 1, wc = wid & 1;
    const int l16 = lane & 15, lg = lane >> 4;
    const int xbase = (sBase >> 5) * 4096;

    f4v acc[2][2] = {};

#pragma unroll 1
    for (int ch = 0; ch < 2; ++ch) {
        __syncthreads();   // WAR vs previous chunk's frag reads
        // ---- A tile: Win[kBase+row][ch*64 + c], 64x64, coalesced float4
#pragma unroll
        for (int it = 0; it < 4; ++it) {
            int idx = it * 256 + tid;
            int row = idx >> 4, c4 = (idx & 15) * 4;
            const float4 w = *(const float4*)&Win[(kBase + row) * 128 + ch * 64 + c4];
            ushort4 hi, lo;
            hi.x = f2bf(w.x); lo.x = f2bf(w.x - bf2f(hi.x));
            hi.y = f2bf(w.y); lo.y = f2bf(w.y - bf2f(hi.y));
            hi.z = f2bf(w.z); lo.z = f2bf(w.z - bf2f(hi.z));
            hi.w = f2bf(w.w); lo.w = f2bf(w.w - bf2f(hi.w));
            *(ushort4*)&Ah[row * LDA + c4] = hi;
            *(ushort4*)&Al[row * LDA + c4] = lo;
        }
        // ---- B tile: B[srow][l] = x_p[sBase+srow][ch*64+l], coalesced reads
#pragma unroll
        for (int it = 0; it < 16; ++it) {
            int idx = it * 256 + tid;
            int srow = idx & 63, l = idx >> 6;
            float val = x[xbase + (srow >> 5) * 4096 + (ch * 64 + l) * 32 + (srow & 31)];
            unsigned short hv = f2bf(val);
            Bh[srow * LDA + l] = hv;
            Bl[srow * LDA + l] = f2bf(val - bf2f(hv));
        }
        __syncthreads();
        // ---- compute: 2 K-steps of 32, 3 split products each
#pragma unroll
        for (int kk = 0; kk < 2; ++kk) {
            s8v ah[2], al[2], bh[2], bl[2];
#pragma unroll
            for (int r = 0; r < 2; ++r) {
                int row = wr * 32 + r * 16 + l16;
                ah[r] = *(s8v*)&Ah[row * LDA + kk * 32 + lg * 8];
                al[r] = *(s8v*)&Al[row * LDA + kk * 32 + lg * 8];
            }
#pragma unroll
            for (int c = 0; c < 2; ++c) {
                int col = wc * 32 + c * 16 + l16;
                bh[c] = *(s8v*)&Bh[col * LDA + kk * 32 + lg * 8];
                bl[c] = *(s8v*)&Bl[col * LDA + kk * 32 + lg * 8];
            }
#pragma unroll
            for (int r = 0; r < 2; ++r)
#pragma unroll
                for (int c = 0; c < 2; ++c) {
                    acc[r][c] = __builtin_amdgcn_mfma_f32_16x16x32_bf16(
                        ah[r], bh[c], acc[r][c], 0, 0, 0);
                    acc[r][c] = __builtin_amdgcn_mfma_f32_16x16x32_bf16(
                        ah[r], bl[c], acc[r][c], 0, 0, 0);
                    acc[r][c] = __builtin_amdgcn_mfma_f32_16x16x32_bf16(
                        al[r], bh[c], acc[r][c], 0, 0, 0);
                }
        }
    }
    // ---- epilogue: D[row=k][col=s] -> h[s*4096+k], rows contiguous per reg
#pragma unroll
    for (int r = 0; r < 2; ++r) {
        const int kg = kBase + wr * 32 + r * 16 + lg * 4;
        const float4 b4 = *(const float4*)&bin[kg];
#pragma unroll
        for (int c = 0; c < 2; ++c) {
            const int sg = sBase + wc * 32 + c * 16 + l16;
            float4 o;
            o.x = acc[r][c][0] + b4.x + 1e-6f;
            o.y = acc[r][c][1] + b4.y + 1e-6f;
            o.z = acc[r][c][2] + b4.z + 1e-6f;
            o.w = acc[r][c][3] + b4.w + 1e-6f;
            *(float4*)&h[(size_t)sg * 4096 + kg] = o;
        }
    }
}

// Packed-complex Rot gate on register bit Q (v_pk_fma_f32 path, verified r8).
#define ROT_PK(GI, Q)                                                     \
    {                                                                     \
        const float* U = Ug[GI];                                          \
        const float u00r = U[0], u01r = U[2], u10r = U[4], u11r = U[6];   \
        const v2f i00 = {-U[1], U[1]}, i01 = {-U[3], U[3]};               \
        const v2f i10 = {-U[5], U[5]}, i11 = {-U[7], U[7]};               \
        _Pragma("unroll")                                                 \
        for (int j = 0; j < 16; ++j)                                      \
            if (!((j >> (Q)) & 1)) {                                      \
                const int j1 = j | (1 << (Q));                            \
                v2f a0 = v[j], a1 = v[j1];                                \
                v2f s0 = SWV(a0), s1 = SWV(a1);                           \
                v[j]  = a0 * u00r + s0 * i00 + a1 * u01r + s1 * i01;      \
                v[j1] = a0 * u10r + s0 * i10 + a1 * u11r + s1 * i11;      \
            }                                                             \
    }

// ---------------- Kernel B: register-resident qsim with corner-turns ---------
__global__ __launch_bounds__(256, 2) void qsim_kernel(
        const float* __restrict__ h, const float* __restrict__ qw,
        const float* __restrict__ Wout, const float* __restrict__ bout,
        float* __restrict__ out, QConsts C) {
    __shared__ v2f st[DIM];                 // 32 KB
    __shared__ float Ug[NLAYERS * NQ][8];   // gate matrices
    __shared__ float red[4];
    __shared__ float wred[4][NQ];
    __shared__ float zsh[NQ];

    const int tid = threadIdx.x;
    const int samp = blockIdx.x;
    const int lane = tid & 63, wv = tid >> 6;

    // ---- Rot matrices (PennyLane Rot = RZ(om)RY(th)RZ(phi))
    if (tid < NLAYERS * NQ) {
        float phi = qw[tid * 3 + 0];
        float th  = qw[tid * 3 + 1];
        float om  = qw[tid * 3 + 2];
        float s, c, sa, ca, sb, cb;
        sincosf(0.5f * th, &s, &c);
        sincosf(0.5f * (phi + om), &sa, &ca);
        sincosf(0.5f * (phi - om), &sb, &cb);
        Ug[tid][0] =  c * ca;  Ug[tid][1] = -c * sa;   // u00
        Ug[tid][2] = -s * cb;  Ug[tid][3] = -s * sb;   // u01
        Ug[tid][4] =  s * cb;  Ug[tid][5] = -s * sb;   // u10
        Ug[tid][6] =  c * ca;  Ug[tid][7] =  c * sa;   // u11
    }

    // ---- load h row directly into state (coalesced), compute norm
    v2f v[16];
    float ss = 0.f;
#pragma unroll
    for (int j = 0; j < 16; ++j) {
        float t = h[(size_t)samp * DIM + (j << 8) + tid];
        v[j][0] = t;
        v[j][1] = 0.f;
        ss += t * t;
    }
#pragma unroll
    for (int o = 32; o > 0; o >>= 1) ss += __shfl_xor(ss, o);
    if (lane == 0) red[wv] = ss;
    __syncthreads();     // also covers Ug init
    const float inv = 1.0f / sqrtf(red[0] + red[1] + red[2] + red[3]);
#pragma unroll
    for (int j = 0; j < 16; ++j) v[j][0] *= inv;

    const int tHi = tid >> 4, tLo = tid & 15;

#pragma unroll 1
    for (int l = 0; l < NLAYERS; ++l) {
        const int gb = l * NQ;

        // ---- stage A: wires 0-3 on reg bit q (amp bit 8+q, wire 3-q)
        ROT_PK(gb + 3, 0)
        ROT_PK(gb + 2, 1)
        ROT_PK(gb + 1, 2)
        ROT_PK(gb + 0, 3)

        // ---- X1: A -> B.  phi1(a) = a ^ ((a>>8)&15)
#pragma unroll
        for (int j = 0; j < 16; ++j) st[(j << 8) | (tid ^ j)] = v[j];
        __syncthreads();
        {
            const int rb = (tHi << 8) | (tLo ^ tHi);
#pragma unroll
            for (int j = 0; j < 16; ++j) v[j] = st[rb | (j << 4)];
        }
        __syncthreads();

        // ---- stage B: wires 4-7 on reg bit q (amp bit 4+q, wire 7-q)
        ROT_PK(gb + 7, 0)
        ROT_PK(gb + 6, 1)
        ROT_PK(gb + 5, 2)
        ROT_PK(gb + 4, 3)

        // ---- X2: B -> C.  phi2(a) = a ^ ((a>>4)&15)
        {
            const int hi8 = tHi << 8;
#pragma unroll
            for (int j = 0; j < 16; ++j)
                st[hi8 | (j << 4) | (tLo ^ j)] = v[j];
        }
        __syncthreads();
        {
            const int rb = tid << 4;
#pragma unroll
            for (int j = 0; j < 16; ++j) v[j] = st[rb | (tLo ^ j)];
        }
        __syncthreads();

        // ---- stage C: wires 8-11 on reg bit q (amp bit q, wire 11-q)
        ROT_PK(gb + 11, 0)
        ROT_PK(gb + 10, 1)
        ROT_PK(gb + 9, 2)
        ROT_PK(gb + 8, 3)

        // ---- X3: CNOT perm + back to canonical (host-searched swizzle)
        {
            unsigned gval = 0, pbase = 0;
#pragma unroll
            for (int b = 0; b < 8; ++b)
                if ((tid >> b) & 1) { gval ^= C.g[l][b]; pbase ^= C.p[l][b]; }
            const int wb = tid << 4;
#pragma unroll
            for (int j = 0; j < 16; ++j) st[wb | (j ^ (int)gval)] = v[j];
            __syncthreads();
            const unsigned c8 = C.p[l][8], c9 = C.p[l][9];
            const unsigned c10 = C.p[l][10], c11 = C.p[l][11];
#pragma unroll
            for (int j = 0; j < 16; ++j) {
                unsigned s = pbase;
                if (j & 1) s ^= c8;
                if (j & 2) s ^= c9;
                if (j & 4) s ^= c10;
                if (j & 8) s ^= c11;
                v[j] = st[s];
            }
            __syncthreads();
        }
    }

    // ---- PauliZ expvals.  a = (j<<8)|tid; sign_i = bit (11-i) of a.
    float P = 0.f;
    float z03[4] = {0.f, 0.f, 0.f, 0.f};
#pragma unroll
    for (int j = 0; j < 16; ++j) {
        float pr = v[j][0] * v[j][0] + v[j][1] * v[j][1];
        P += pr;
#pragma unroll
        for (int i = 0; i < 4; ++i)
            z03[i] += ((j >> (3 - i)) & 1) ? -pr : pr;
    }
    float zv[12];
#pragma unroll
    for (int i = 0; i < 4; ++i) zv[i] = z03[i];
#pragma unroll
    for (int i = 4; i < 12; ++i)
        zv[i] = ((tid >> (11 - i)) & 1) ? -P : P;
#pragma unroll
    for (int i = 0; i < 12; ++i) {
        float z = zv[i];
#pragma unroll
        for (int o = 32; o > 0; o >>= 1) z += __shfl_xor(z, o);
        if (lane == 0) wred[wv][i] = z;
    }
    __syncthreads();
    if (tid < NQ)
        zsh[tid] = wred[0][tid] + wred[1][tid] + wred[2][tid] + wred[3][tid];
    __syncthreads();

    if (tid < 96) {
        float acc = bout[tid];
#pragma unroll
        for (int i = 0; i < NQ; ++i) acc += zsh[i] * Wout[tid * NQ + i];
        int b = samp >> 5, m = samp & 31;
        out[b * (96 * 32) + tid * 32 + m] = acc;
    }
}

extern "C" void kernel_launch(void* const* d_in, const int* in_sizes, int n_in,
                              void* d_out, int out_size, void* d_ws, size_t ws_size,
                              hipStream_t stream) {
    const float* x    = (const float*)d_in[0];
    const float* Win  = (const float*)d_in[1];
    const float* bin  = (const float*)d_in[2];
    const float* qw   = (const float*)d_in[3];
    const float* Wout = (const float*)d_in[4];
    const float* bout = (const float*)d_in[5];
    float* h = (float*)d_ws;   // 32 MB scratch

    QConsts C = host_consts();

    gemm_in_mfma<<<dim3(64, 32), 256, 0, stream>>>(x, Win, bin, h);
    qsim_kernel<<<dim3(NSAMP), 256, 0, stream>>>(h, qw, Wout, bout,
                                                 (float*)d_out, C);
}

// Round 12
// 75.215 us; speedup vs baseline: 3.2676x; 1.4282x over previous
//
#include <hip/hip_runtime.h>
#include <math.h>

#define NQ 12
#define DIM 4096
#define NSAMP 2048
#define NLAYERS 4

typedef _Float16 h8v __attribute__((ext_vector_type(8)));  // 8 fp16
typedef short s8v __attribute__((ext_vector_type(8)));     // 8 bf16 raw bits
typedef float f4v __attribute__((ext_vector_type(4)));

// X3 scatter: amplitude computed for pre-CNOT index o lands at b = M^{-1} o.
// b = XOR over set bits j of o of mv[l][j] (columns of M^{-1}).
struct QMasks { unsigned short mv[NLAYERS][12]; };

static void cnot_masks(int l, unsigned* m) {
    int r = l % (NQ - 1) + 1;
    for (int j = 0; j < NQ; ++j) {
        unsigned v = 1u << j;
        for (int k = NQ - 1; k >= 0; --k) {
            int c = k, t = (k + r) % NQ;
            int pc = NQ - 1 - c, pt = NQ - 1 - t;
            if ((v >> pc) & 1u) v ^= (1u << pt);
        }
        m[j] = v;
    }
}

static QMasks host_masks() {
    QMasks Q{};
    for (int l = 0; l < NLAYERS; ++l) {
        unsigned m[12];
        cnot_masks(l, m);
        unsigned A[12], I[12];
        for (int k = 0; k < 12; ++k) {          // rows of M (columns are m[j])
            unsigned row = 0;
            for (int j = 0; j < 12; ++j) row |= ((m[j] >> k) & 1u) << j;
            A[k] = row; I[k] = 1u << k;
        }
        for (int c = 0; c < 12; ++c) {          // Gauss-Jordan over GF(2)
            int p = c; while (!((A[p] >> c) & 1u)) ++p;
            unsigned ta = A[p], ti = I[p]; A[p] = A[c]; I[p] = I[c]; A[c] = ta; I[c] = ti;
            for (int r2 = 0; r2 < 12; ++r2)
                if (r2 != c && ((A[r2] >> c) & 1u)) { A[r2] ^= A[c]; I[r2] ^= I[c]; }
        }
        for (int j = 0; j < 12; ++j) {          // columns of M^{-1}
            unsigned colv = 0;
            for (int k = 0; k < 12; ++k) colv |= ((I[k] >> j) & 1u) << k;
            Q.mv[l][j] = (unsigned short)colv;
        }
    }
    return Q;
}

__device__ __forceinline__ unsigned short f2bf(float f) {
    unsigned u = __builtin_bit_cast(unsigned, f);
    return (unsigned short)((u + 0x7FFFu + ((u >> 16) & 1u)) >> 16);   // RNE
}
__device__ __forceinline__ float bf2f(unsigned short b) {
    unsigned u = ((unsigned)b) << 16;
    return __builtin_bit_cast(float, u);
}
__device__ __forceinline__ unsigned packh(float re, float im) {
    unsigned short rb = __builtin_bit_cast(unsigned short, (_Float16)re);
    unsigned short ib = __builtin_bit_cast(unsigned short, (_Float16)im);
    return (unsigned)rb | ((unsigned)ib << 16);
}
__device__ __forceinline__ float h2f(unsigned short h) {
    return (float)__builtin_bit_cast(_Float16, h);
}

// ---------------- Kernel A: MFMA bf16-split input GEMM + fp16 gate prep ------
#define LDA 72
__global__ __launch_bounds__(256) void gemm_in_mfma(
        const float* __restrict__ x, const float* __restrict__ Win,
        const float* __restrict__ bin, const float* __restrict__ qw,
        unsigned short* __restrict__ h16, h8v* __restrict__ gates) {
    __shared__ unsigned short Ah[64 * LDA], Al[64 * LDA];
    __shared__ unsigned short Bh[64 * LDA], Bl[64 * LDA];
    const int tid = threadIdx.x;

    if (blockIdx.y == 32) {
        // ---- gate prep: stage s = layer*3 + sigma; G = kron of 4 Rot gates
        const int s = blockIdx.x;
        if (s >= 12 || tid >= 64) return;
        const int layer = s / 3, sg = s % 3;
        const int row = tid & 15, hi = tid >> 4;
        float ur[4][2][2], ui[4][2][2];
        for (int t = 0; t < 4; ++t) {
            const float* q = qw + (layer * NQ + sg * 4 + t) * 3;
            float sn, cs, sa, ca, sb, cb;
            sincosf(0.5f * q[1], &sn, &cs);
            sincosf(0.5f * (q[0] + q[2]), &sa, &ca);
            sincosf(0.5f * (q[0] - q[2]), &sb, &cb);
            ur[t][0][0] =  cs * ca; ui[t][0][0] = -cs * sa;
            ur[t][0][1] = -sn * cb; ui[t][0][1] = -sn * sb;
            ur[t][1][0] =  sn * cb; ui[t][1][0] = -sn * sb;
            ur[t][1][1] =  cs * ca; ui[t][1][1] =  cs * sa;
        }
        h8v arh, arl, aih, ail;
        for (int mm = 0; mm < 4; ++mm) {
            int m = hi * 4 + mm;
            float gr = 1.f, gi = 0.f;
            for (int t = 0; t < 4; ++t) {
                int rb = (row >> (3 - t)) & 1, cb2 = (m >> (3 - t)) & 1;
                float ar = ur[t][rb][cb2], ai = ui[t][rb][cb2];
                float nr = gr * ar - gi * ai, ni = gr * ai + gi * ar;
                gr = nr; gi = ni;
            }
            // A_re[k=2m]=Gr, [2m+1]=-Gi ; A_im[2m]=Gi, [2m+1]=Gr  (fp16 hi/lo)
            float vv[4] = {gr, -gi, gi, gr};
            _Float16 hh;
            hh = (_Float16)vv[0]; arh[2*mm]   = hh; arl[2*mm]   = (_Float16)(vv[0] - (float)hh);
            hh = (_Float16)vv[1]; arh[2*mm+1] = hh; arl[2*mm+1] = (_Float16)(vv[1] - (float)hh);
            hh = (_Float16)vv[2]; aih[2*mm]   = hh; ail[2*mm]   = (_Float16)(vv[2] - (float)hh);
            hh = (_Float16)vv[3]; aih[2*mm+1] = hh; ail[2*mm+1] = (_Float16)(vv[3] - (float)hh);
        }
        gates[(s * 4 + 0) * 64 + tid] = arh;
        gates[(s * 4 + 1) * 64 + tid] = arl;
        gates[(s * 4 + 2) * 64 + tid] = aih;
        gates[(s * 4 + 3) * 64 + tid] = ail;
        return;
    }

    // ---- GEMM (verified round 9), fp16 output
    const int kBase = blockIdx.x * 64;
    const int sBase = blockIdx.y * 64;
    const int lane = tid & 63, wid = tid >> 6;
    const int wr = wid >> 1, wc = wid & 1;
    const int l16 = lane & 15, lg = lane >> 4;
    const int xbase = (sBase >> 5) * 4096;
    f4v acc[2][2] = {};

#pragma unroll 1
    for (int ch = 0; ch < 2; ++ch) {
        __syncthreads();
#pragma unroll
        for (int it = 0; it < 4; ++it) {
            int idx = it * 256 + tid;
            int row = idx >> 4, c4 = (idx & 15) * 4;
            const float4 w = *(const float4*)&Win[(kBase + row) * 128 + ch * 64 + c4];
            ushort4 hi4, lo4;
            hi4.x = f2bf(w.x); lo4.x = f2bf(w.x - bf2f(hi4.x));
            hi4.y = f2bf(w.y); lo4.y = f2bf(w.y - bf2f(hi4.y));
            hi4.z = f2bf(w.z); lo4.z = f2bf(w.z - bf2f(hi4.z));
            hi4.w = f2bf(w.w); lo4.w = f2bf(w.w - bf2f(hi4.w));
            *(ushort4*)&Ah[row * LDA + c4] = hi4;
            *(ushort4*)&Al[row * LDA + c4] = lo4;
        }
#pragma unroll
        for (int it = 0; it < 16; ++it) {
            int idx = it * 256 + tid;
            int srow = idx & 63, l = idx >> 6;
            float val = x[xbase + (srow >> 5) * 4096 + (ch * 64 + l) * 32 + (srow & 31)];
            unsigned short hv = f2bf(val);
            Bh[srow * LDA + l] = hv;
            Bl[srow * LDA + l] = f2bf(val - bf2f(hv));
        }
        __syncthreads();
#pragma unroll
        for (int kk = 0; kk < 2; ++kk) {
            s8v ah[2], al2[2], bh[2], bl[2];
#pragma unroll
            for (int r = 0; r < 2; ++r) {
                int row = wr * 32 + r * 16 + l16;
                ah[r]  = *(s8v*)&Ah[row * LDA + kk * 32 + lg * 8];
                al2[r] = *(s8v*)&Al[row * LDA + kk * 32 + lg * 8];
            }
#pragma unroll
            for (int c = 0; c < 2; ++c) {
                int col = wc * 32 + c * 16 + l16;
                bh[c] = *(s8v*)&Bh[col * LDA + kk * 32 + lg * 8];
                bl[c] = *(s8v*)&Bl[col * LDA + kk * 32 + lg * 8];
            }
#pragma unroll
            for (int r = 0; r < 2; ++r)
#pragma unroll
                for (int c = 0; c < 2; ++c) {
                    acc[r][c] = __builtin_amdgcn_mfma_f32_16x16x32_bf16(ah[r],  bh[c], acc[r][c], 0, 0, 0);
                    acc[r][c] = __builtin_amdgcn_mfma_f32_16x16x32_bf16(ah[r],  bl[c], acc[r][c], 0, 0, 0);
                    acc[r][c] = __builtin_amdgcn_mfma_f32_16x16x32_bf16(al2[r], bh[c], acc[r][c], 0, 0, 0);
                }
        }
    }
#pragma unroll
    for (int r = 0; r < 2; ++r) {
        const int kg = kBase + wr * 32 + r * 16 + lg * 4;
        const float4 b4 = *(const float4*)&bin[kg];
#pragma unroll
        for (int c = 0; c < 2; ++c) {
            const int sg2 = sBase + wc * 32 + c * 16 + l16;
            ushort4 o;
            o.x = __builtin_bit_cast(unsigned short, (_Float16)(acc[r][c][0] + b4.x + 1e-6f));
            o.y = __builtin_bit_cast(unsigned short, (_Float16)(acc[r][c][1] + b4.y + 1e-6f));
            o.z = __builtin_bit_cast(unsigned short, (_Float16)(acc[r][c][2] + b4.z + 1e-6f));
            o.w = __builtin_bit_cast(unsigned short, (_Float16)(acc[r][c][3] + b4.w + 1e-6f));
            *(ushort4*)&h16[(size_t)sg2 * 4096 + kg] = o;
        }
    }
}

// ---------------- Kernel B: MFMA state-vector simulator (fp16 state) ---------
// State fp16 re/im packed per word: word[col*18 + axis].  Per layer 3 stages:
//  s0: axis=n2, col=n1*16+n0 ; s1: axis=n1, col=n2*16+n0 ; s2: axis=n0,
//  col=n2*16+n1, CNOT perm (b = M^{-1} o) folded into s2 scatter -> canonical.
#define BUFW 4608   // 256 cols * 18 words

__global__ __launch_bounds__(256, 2) void qsim_mfma(
        const unsigned short* __restrict__ h16, const h8v* __restrict__ gates,
        const float* __restrict__ Wout, const float* __restrict__ bout,
        float* __restrict__ out, QMasks Q) {
    __shared__ unsigned lds[2 * BUFW];
    __shared__ float red[4];
    __shared__ float wred[4][13];
    __shared__ float zsh[13];

    const int tid = threadIdx.x;
    const int samp = blockIdx.x;
    const int lane = tid & 63;
    const int wv = tid >> 6;
    const int l16 = tid & 15;
    const int hi = (tid >> 4) & 3;
    const f4v fz = {0.f, 0.f, 0.f, 0.f};

    // ---- load h row (fp16), norm, write canonical layout (col=tid, axis=j)
    float vr[16]; float ss = 0.f;
#pragma unroll
    for (int j = 0; j < 16; ++j) {
        float f = h2f(h16[samp * DIM + j * 256 + tid]);
        vr[j] = f; ss += f * f;
    }
#pragma unroll
    for (int o = 32; o > 0; o >>= 1) ss += __shfl_xor(ss, o);
    if (lane == 0) red[wv] = ss;
    __syncthreads();
    const float inv = 1.0f / sqrtf(red[0] + red[1] + red[2] + red[3]);
#pragma unroll
    for (int j = 0; j < 16; ++j)
        lds[tid * 18 + j] = packh(vr[j] * inv, 0.f);
    __syncthreads();

    h8v ArH, ArL, AiH, AiL;
    f4v dre, dim_;

#define LOAD_FRAGS(S) { const h8v* gp = gates + (S) * 256 + lane;             \
    ArH = gp[0]; ArL = gp[64]; AiH = gp[128]; AiL = gp[192]; }

#define TILE_COMPUTE(RB, CG) {                                                \
    unsigned ra = (RB) + ((unsigned)(((CG) << 4) | l16)) * 18u + (hi << 2);   \
    uint2 w0 = *(const uint2*)&lds[ra];                                       \
    uint2 w1 = *(const uint2*)&lds[ra + 2];                                   \
    uint4 bw; bw.x = w0.x; bw.y = w0.y; bw.z = w1.x; bw.w = w1.y;             \
    h8v bf = __builtin_bit_cast(h8v, bw);                                     \
    dre = __builtin_amdgcn_mfma_f32_16x16x32_f16(ArH, bf, fz, 0, 0, 0);       \
    dre = __builtin_amdgcn_mfma_f32_16x16x32_f16(ArL, bf, dre, 0, 0, 0);      \
    dim_ = __builtin_amdgcn_mfma_f32_16x16x32_f16(AiH, bf, fz, 0, 0, 0);      \
    dim_ = __builtin_amdgcn_mfma_f32_16x16x32_f16(AiL, bf, dim_, 0, 0, 0); }

#define WRITE_S0(WB, CG) {                                                    \
    unsigned wa = (WB) + 1152u * hi + 18u * l16 + (unsigned)(CG);             \
    lds[wa]        = packh(dre[0], dim_[0]);                                  \
    lds[wa + 288]  = packh(dre[1], dim_[1]);                                  \
    lds[wa + 576]  = packh(dre[2], dim_[2]);                                  \
    lds[wa + 864]  = packh(dre[3], dim_[3]); }

#define WRITE_S1(WB, CG) {                                                    \
    unsigned wa = (WB) + 288u * (unsigned)(CG) + 72u * hi + (unsigned)l16;    \
    lds[wa]       = packh(dre[0], dim_[0]);                                   \
    lds[wa + 18]  = packh(dre[1], dim_[1]);                                   \
    lds[wa + 36]  = packh(dre[2], dim_[2]);                                   \
    lds[wa + 54]  = packh(dre[3], dim_[3]); }

// o = CG<<8 | l16<<4 | hi<<2 | reg ;  b = XOR of mv over set bits of o;
// write canonical: word = (b&255)*18 + (b>>8)
#define RUN_LAYER(L, A, B)                                                    \
    LOAD_FRAGS(3 * (L) + 0)                                                   \
    { TILE_COMPUTE(A, 4 * wv + 0) WRITE_S0(B, 4 * wv + 0) }                   \
    { TILE_COMPUTE(A, 4 * wv + 1) WRITE_S0(B, 4 * wv + 1) }                   \
    { TILE_COMPUTE(A, 4 * wv + 2) WRITE_S0(B, 4 * wv + 2) }                   \
    { TILE_COMPUTE(A, 4 * wv + 3) WRITE_S0(B, 4 * wv + 3) }                   \
    __syncthreads();                                                          \
    LOAD_FRAGS(3 * (L) + 1)                                                   \
    { TILE_COMPUTE(B, 4 * wv + 0) WRITE_S1(A, 4 * wv + 0) }                   \
    { TILE_COMPUTE(B, 4 * wv + 1) WRITE_S1(A, 4 * wv + 1) }                   \
    { TILE_COMPUTE(B, 4 * wv + 2) WRITE_S1(A, 4 * wv + 2) }                   \
    { TILE_COMPUTE(B, 4 * wv + 3) WRITE_S1(A, 4 * wv + 3) }                   \
    __syncthreads();                                                          \
    LOAD_FRAGS(3 * (L) + 2)                                                   \
    {                                                                         \
        unsigned bb0 = 0;                                                     \
        if (hi & 1)  bb0 ^= Q.mv[L][2];  if (hi & 2)  bb0 ^= Q.mv[L][3];      \
        if (l16 & 1) bb0 ^= Q.mv[L][4];  if (l16 & 2) bb0 ^= Q.mv[L][5];      \
        if (l16 & 4) bb0 ^= Q.mv[L][6];  if (l16 & 8) bb0 ^= Q.mv[L][7];      \
        if (wv & 1)  bb0 ^= Q.mv[L][10]; if (wv & 2)  bb0 ^= Q.mv[L][11];     \
        _Pragma("unroll")                                                     \
        for (int T = 0; T < 4; ++T) {                                         \
            TILE_COMPUTE(A, 4 * wv + T)                                       \
            unsigned bb = bb0;                                                \
            if (T & 1) bb ^= Q.mv[L][8];                                      \
            if (T & 2) bb ^= Q.mv[L][9];                                      \
            unsigned b0 = bb;                                                 \
            unsigned b1 = bb ^ Q.mv[L][0];                                    \
            unsigned b2 = bb ^ Q.mv[L][1];                                    \
            unsigned b3 = b1 ^ Q.mv[L][1];                                    \
            lds[(B) + (b0 & 255u) * 18u + (b0 >> 8)] = packh(dre[0], dim_[0]); \
            lds[(B) + (b1 & 255u) * 18u + (b1 >> 8)] = packh(dre[1], dim_[1]); \
            lds[(B) + (b2 & 255u) * 18u + (b2 >> 8)] = packh(dre[2], dim_[2]); \
            lds[(B) + (b3 & 255u) * 18u + (b3 >> 8)] = packh(dre[3], dim_[3]); \
        }                                                                     \
    }                                                                         \
    __syncthreads();

    RUN_LAYER(0, 0, BUFW)
    RUN_LAYER(1, BUFW, 0)
    RUN_LAYER(2, 0, BUFW)
    RUN_LAYER(3, BUFW, 0)

    // ---- expvals from canonical buffer 0 (R8-verified): amp a = (j<<8)|tid
    float P = 0.f;
    float z03[4] = {0.f, 0.f, 0.f, 0.f};
#pragma unroll
    for (int j = 0; j < 16; ++j) {
        unsigned w = lds[tid * 18 + j];
        float re = h2f((unsigned short)(w & 0xFFFFu));
        float im = h2f((unsigned short)(w >> 16));
        float pr = re * re + im * im;
        P += pr;
#pragma unroll
        for (int i = 0; i < 4; ++i)
            z03[i] += ((j >> (3 - i)) & 1) ? -pr : pr;
    }
    float zv[12];
#pragma unroll
    for (int i = 0; i < 4; ++i) zv[i] = z03[i];
#pragma unroll
    for (int i = 4; i < 12; ++i)
        zv[i] = ((tid >> (11 - i)) & 1) ? -P : P;
#pragma unroll
    for (int i = 0; i < 12; ++i) {
        float z = zv[i];
#pragma unroll
        for (int o = 32; o > 0; o >>= 1) z += __shfl_xor(z, o);
        if (lane == 0) wred[wv][i] = z;
    }
    {
        float v = P;
#pragma unroll
        for (int o = 32; o > 0; o >>= 1) v += __shfl_xor(v, o);
        if (lane == 0) wred[wv][12] = v;
    }
    __syncthreads();
    if (tid < 13)
        zsh[tid] = wred[0][tid] + wred[1][tid] + wred[2][tid] + wred[3][tid];
    __syncthreads();

    if (tid < 96) {
        const float invP = 1.0f / zsh[12];   // renormalize fp16 drift
        float acc = bout[tid];
#pragma unroll
        for (int i = 0; i < 12; ++i) acc += zsh[i] * invP * Wout[tid * 12 + i];
        int b = samp >> 5, m = samp & 31;
        out[b * (96 * 32) + tid * 32 + m] = acc;
    }
}

extern "C" void kernel_launch(void* const* d_in, const int* in_sizes, int n_in,
                              void* d_out, int out_size, void* d_ws, size_t ws_size,
                              hipStream_t stream) {
    const float* x    = (const float*)d_in[0];
    const float* Win  = (const float*)d_in[1];
    const float* bin  = (const float*)d_in[2];
    const float* qw   = (const float*)d_in[3];
    const float* Wout = (const float*)d_in[4];
    const float* bout = (const float*)d_in[5];
    unsigned short* h16 = (unsigned short*)d_ws;                       // 16 MB
    h8v* gates = (h8v*)((char*)d_ws + (size_t)NSAMP * DIM * 2);        // 48 KB

    QMasks Q = host_masks();

    gemm_in_mfma<<<dim3(64, 33), 256, 0, stream>>>(x, Win, bin, qw, h16, gates);
    qsim_mfma<<<dim3(NSAMP), 256, 0, stream>>>(h16, gates, Wout, bout,
                                               (float*)d_out, Q);
}